// Round 1
// baseline (1059.795 us; speedup 1.0000x reference)
//
#include <hip/hip_runtime.h>

// ---------------------------------------------------------------------------
// GAT encoder, 2 layers, N=100K nodes, E=1.6M edges (+N self loops), F=128,
// heads=2 x 64ch. Strategy:
//   1. Build dst-CSR once (histogram -> scan -> scatter), reused by both layers.
//   2. Per layer: fp32 GEMM h = x@W with fused alpha_src/alpha_dst epilogue,
//      then per-node wave aggregation: out = elu( sum_e w_e h[src_e] / sum_e w_e + b ).
//   Softmax max-subtraction skipped (logits bounded ~|2|, exp safe in fp32).
// ---------------------------------------------------------------------------

__global__ __launch_bounds__(256) void k_hist(const int* __restrict__ ei,
                                              int* __restrict__ deg, int E, int n) {
    int i = blockIdx.x * blockDim.x + threadIdx.x;
    if (i < E) {
        atomicAdd(&deg[ei[E + i]], 1);          // dst half of edge_index
    } else if (i < E + n) {
        atomicAdd(&deg[i - E], 1);              // self loop
    }
}

__global__ __launch_bounds__(1024) void k_scan_block(const int* __restrict__ deg,
                                                     int* __restrict__ off,
                                                     int* __restrict__ bsum, int n) {
    __shared__ int tmp[1024];
    int t = threadIdx.x;
    int i = blockIdx.x * 1024 + t;
    int v = (i < n) ? deg[i] : 0;
    tmp[t] = v;
    __syncthreads();
    for (int d = 1; d < 1024; d <<= 1) {
        int a = (t >= d) ? tmp[t - d] : 0;
        __syncthreads();
        tmp[t] += a;
        __syncthreads();
    }
    if (i < n) off[i] = tmp[t] - v;             // exclusive
    if (t == 1023) bsum[blockIdx.x] = tmp[t];
}

__global__ __launch_bounds__(128) void k_scan_bsum(int* __restrict__ bsum, int nb) {
    __shared__ int tmp[128];
    int t = threadIdx.x;
    int v = (t < nb) ? bsum[t] : 0;
    tmp[t] = v;
    __syncthreads();
    for (int d = 1; d < 128; d <<= 1) {
        int a = (t >= d) ? tmp[t - d] : 0;
        __syncthreads();
        tmp[t] += a;
        __syncthreads();
    }
    if (t < nb) bsum[t] = tmp[t] - v;           // exclusive over block sums
}

__global__ __launch_bounds__(1024) void k_scan_add(int* __restrict__ off,
                                                   const int* __restrict__ bsum, int n) {
    int i = blockIdx.x * 1024 + threadIdx.x;
    if (i < n) off[i] += bsum[blockIdx.x];
}

__global__ __launch_bounds__(256) void k_scatter(const int* __restrict__ ei,
                                                 const int* __restrict__ off,
                                                 int* __restrict__ cursor,
                                                 int* __restrict__ csr, int E, int n) {
    int i = blockIdx.x * blockDim.x + threadIdx.x;
    if (i < E) {
        int d = ei[E + i];
        int p = atomicAdd(&cursor[d], 1);
        csr[off[d] + p] = ei[i];
    } else if (i < E + n) {
        int nn = i - E;
        int p = atomicAdd(&cursor[nn], 1);
        csr[off[nn] + p] = nn;
    }
}

// GEMM: H[row, col] = sum_k X[row,k] * W[k,col], 128x128 W, fused alpha epilogue.
// 8 rows/block, 32 threads per row, 4 cols per thread (float4).
__global__ __launch_bounds__(256) void k_gemm_alpha(
    const float* __restrict__ X, const float* __restrict__ W,
    const float* __restrict__ a_src, const float* __restrict__ a_dst,
    float* __restrict__ H, float* __restrict__ as_out, float* __restrict__ ad_out,
    int n) {
    __shared__ float xs[8 * 128];
    int t = threadIdx.x;
    int rowBase = blockIdx.x * 8;
    {   // cooperative load of 8 rows (256 threads x float4 = 1024 floats)
        float4 v = make_float4(0.f, 0.f, 0.f, 0.f);
        int elem = t * 4;
        if (rowBase + (elem >> 7) < n)
            v = ((const float4*)(X + (size_t)rowBase * 128))[t];
        ((float4*)xs)[t] = v;
    }
    __syncthreads();
    int r = t >> 5, c32 = t & 31;
    int row = rowBase + r;
    float4 acc = make_float4(0.f, 0.f, 0.f, 0.f);
    const float4* W4 = (const float4*)W;
#pragma unroll 8
    for (int k = 0; k < 128; ++k) {
        float xk = xs[r * 128 + k];
        float4 w = W4[k * 32 + c32];
        acc.x += xk * w.x; acc.y += xk * w.y; acc.z += xk * w.z; acc.w += xk * w.w;
    }
    if (row < n) {
        ((float4*)(H + (size_t)row * 128))[c32] = acc;
        float4 as4 = ((const float4*)a_src)[c32];
        float4 ad4 = ((const float4*)a_dst)[c32];
        float ps = acc.x * as4.x + acc.y * as4.y + acc.z * as4.z + acc.w * as4.w;
        float pd = acc.x * ad4.x + acc.y * ad4.y + acc.z * ad4.z + acc.w * ad4.w;
#pragma unroll
        for (int m = 8; m >= 1; m >>= 1) {
            ps += __shfl_xor(ps, m, 16);
            pd += __shfl_xor(pd, m, 16);
        }
        if ((c32 & 15) == 0) {
            int head = c32 >> 4;
            as_out[row * 2 + head] = ps;
            ad_out[row * 2 + head] = pd;
        }
    }
}

// Aggregation: one wave per node. lane c holds head0 ch c and head1 ch c.
__global__ __launch_bounds__(256) void k_agg(
    const float* __restrict__ H, const float* __restrict__ as,
    const float* __restrict__ ad, const float* __restrict__ bias,
    const int* __restrict__ csr, const int* __restrict__ off,
    const int* __restrict__ deg, float* __restrict__ out, int n) {
    int wave = threadIdx.x >> 6, lane = threadIdx.x & 63;
    int node = blockIdx.x * 4 + wave;
    if (node >= n) return;
    int o = off[node], d = deg[node];
    float ad0 = ad[node * 2], ad1 = ad[node * 2 + 1];
    float acc0 = 0.f, acc1 = 0.f, den0 = 0.f, den1 = 0.f;
    for (int j = 0; j < d; ++j) {
        int s = csr[o + j];
        float as0 = as[s * 2], as1 = as[s * 2 + 1];
        float e0 = as0 + ad0; e0 = e0 >= 0.f ? e0 : 0.2f * e0;
        float e1 = as1 + ad1; e1 = e1 >= 0.f ? e1 : 0.2f * e1;
        float w0 = __expf(e0), w1 = __expf(e1);
        den0 += w0; den1 += w1;
        const float* hrow = H + (size_t)s * 128;
        acc0 += w0 * hrow[lane];
        acc1 += w1 * hrow[64 + lane];
    }
    float r0 = acc0 / den0 + bias[lane];
    float r1 = acc1 / den1 + bias[64 + lane];
    r0 = r0 > 0.f ? r0 : __expf(r0) - 1.f;   // ELU
    r1 = r1 > 0.f ? r1 : __expf(r1) - 1.f;
    out[(size_t)node * 128 + lane] = r0;
    out[(size_t)node * 128 + 64 + lane] = r1;
}

extern "C" void kernel_launch(void* const* d_in, const int* in_sizes, int n_in,
                              void* d_out, int out_size, void* d_ws, size_t ws_size,
                              hipStream_t stream) {
    const float* x   = (const float*)d_in[0];
    const int*   ei  = (const int*)d_in[1];
    const float* W1  = (const float*)d_in[2];
    const float* as1 = (const float*)d_in[3];
    const float* ad1 = (const float*)d_in[4];
    const float* b1  = (const float*)d_in[5];
    const float* W2  = (const float*)d_in[6];
    const float* as2 = (const float*)d_in[7];
    const float* ad2 = (const float*)d_in[8];
    const float* b2  = (const float*)d_in[9];

    const int N = in_sizes[0] / 128;
    const int E = in_sizes[1] / 2;

    // workspace carve-up
    float* h       = (float*)d_ws;                 // N*128
    float* y1      = h + (size_t)N * 128;          // N*128
    float* alpha_s = y1 + (size_t)N * 128;         // 2N
    float* alpha_d = alpha_s + 2 * (size_t)N;      // 2N
    int*   deg     = (int*)(alpha_d + 2 * (size_t)N);
    int*   off     = deg + N;
    int*   cursor  = off + N;
    int*   bsum    = cursor + N;                   // 128
    int*   csr     = bsum + 128;                   // E+N

    hipMemsetAsync(deg, 0, (size_t)N * 4, stream);
    hipMemsetAsync(cursor, 0, (size_t)N * 4, stream);

    int nb = (N + 1023) / 1024;
    k_hist<<<(E + N + 255) / 256, 256, 0, stream>>>(ei, deg, E, N);
    k_scan_block<<<nb, 1024, 0, stream>>>(deg, off, bsum, N);
    k_scan_bsum<<<1, 128, 0, stream>>>(bsum, nb);
    k_scan_add<<<nb, 1024, 0, stream>>>(off, bsum, N);
    k_scatter<<<(E + N + 255) / 256, 256, 0, stream>>>(ei, off, cursor, csr, E, N);

    // layer 1
    k_gemm_alpha<<<(N + 7) / 8, 256, 0, stream>>>(x, W1, as1, ad1, h, alpha_s, alpha_d, N);
    k_agg<<<(N + 3) / 4, 256, 0, stream>>>(h, alpha_s, alpha_d, b1, csr, off, deg, y1, N);

    // layer 2
    k_gemm_alpha<<<(N + 7) / 8, 256, 0, stream>>>(y1, W2, as2, ad2, h, alpha_s, alpha_d, N);
    k_agg<<<(N + 3) / 4, 256, 0, stream>>>(h, alpha_s, alpha_d, b2, csr, off, deg, (float*)d_out, N);
}

// Round 2
// 786.240 us; speedup vs baseline: 1.3479x; 1.3479x over previous
//
#include <hip/hip_runtime.h>

// ---------------------------------------------------------------------------
// GAT encoder, 2 layers, N=100K nodes, E=1.6M edges (+N self loops), F=128,
// heads=2 x 64ch. Strategy:
//   1. Build dst-CSR once (histogram -> scan -> scatter), reused by both layers.
//   2. Per layer: fp32 GEMM h = x@W (W staged in LDS, 4x4 register blocking)
//      with fused alpha_src/alpha_dst epilogue, then per-node wave aggregation:
//      out = elu( sum_e w_e h[src_e] / sum_e w_e + b ).
//   Softmax max-subtraction skipped (logits bounded ~|2|, exp safe in fp32).
// ---------------------------------------------------------------------------

__global__ __launch_bounds__(256) void k_hist(const int* __restrict__ ei,
                                              int* __restrict__ deg, int E, int n) {
    int i = blockIdx.x * blockDim.x + threadIdx.x;
    if (i < E) {
        atomicAdd(&deg[ei[E + i]], 1);          // dst half of edge_index
    } else if (i < E + n) {
        atomicAdd(&deg[i - E], 1);              // self loop
    }
}

__global__ __launch_bounds__(1024) void k_scan_block(const int* __restrict__ deg,
                                                     int* __restrict__ off,
                                                     int* __restrict__ bsum, int n) {
    __shared__ int tmp[1024];
    int t = threadIdx.x;
    int i = blockIdx.x * 1024 + t;
    int v = (i < n) ? deg[i] : 0;
    tmp[t] = v;
    __syncthreads();
    for (int d = 1; d < 1024; d <<= 1) {
        int a = (t >= d) ? tmp[t - d] : 0;
        __syncthreads();
        tmp[t] += a;
        __syncthreads();
    }
    if (i < n) off[i] = tmp[t] - v;             // exclusive
    if (t == 1023) bsum[blockIdx.x] = tmp[t];
}

__global__ __launch_bounds__(128) void k_scan_bsum(int* __restrict__ bsum, int nb) {
    __shared__ int tmp[128];
    int t = threadIdx.x;
    int v = (t < nb) ? bsum[t] : 0;
    tmp[t] = v;
    __syncthreads();
    for (int d = 1; d < 128; d <<= 1) {
        int a = (t >= d) ? tmp[t - d] : 0;
        __syncthreads();
        tmp[t] += a;
        __syncthreads();
    }
    if (t < nb) bsum[t] = tmp[t] - v;           // exclusive over block sums
}

__global__ __launch_bounds__(1024) void k_scan_add(int* __restrict__ off,
                                                   const int* __restrict__ bsum, int n) {
    int i = blockIdx.x * 1024 + threadIdx.x;
    if (i < n) off[i] += bsum[blockIdx.x];
}

__global__ __launch_bounds__(256) void k_scatter(const int* __restrict__ ei,
                                                 const int* __restrict__ off,
                                                 int* __restrict__ cursor,
                                                 int* __restrict__ csr, int E, int n) {
    int i = blockIdx.x * blockDim.x + threadIdx.x;
    if (i < E) {
        int d = ei[E + i];
        int p = atomicAdd(&cursor[d], 1);
        csr[off[d] + p] = ei[i];
    } else if (i < E + n) {
        int nn = i - E;
        int p = atomicAdd(&cursor[nn], 1);
        csr[off[nn] + p] = nn;
    }
}

// GEMM: H[row,col] = sum_k X[row,k]*W[k,col], W 128x128 staged in LDS (two
// 64-row k-halves), X tile 32 rows in LDS, acc[4][4] register blocking.
// Thread t: rgrp = t>>5 owns rows rgrp*4..rgrp*4+3; c32 = t&31 owns cols
// 4*c32..4*c32+3. Fused alpha_src/alpha_dst epilogue.
__global__ __launch_bounds__(256) void k_gemm_alpha(
    const float* __restrict__ X, const float* __restrict__ W,
    const float* __restrict__ a_src, const float* __restrict__ a_dst,
    float* __restrict__ H, float* __restrict__ as_out, float* __restrict__ ad_out,
    int n) {
    __shared__ float xs[32 * 128];   // 16 KB
    __shared__ float ws[64 * 128];   // 32 KB (one k-half of W at a time)
    int t = threadIdx.x;
    int rowBase = blockIdx.x * 32;
    const float4* X4 = (const float4*)X;
    const float4* W4 = (const float4*)W;

    // stage X tile (32 rows x 128 = 1024 float4)
#pragma unroll
    for (int it = 0; it < 4; ++it) {
        int idx = t + it * 256;
        int row = rowBase + (idx >> 5);
        float4 v = make_float4(0.f, 0.f, 0.f, 0.f);
        if (row < n) v = X4[(size_t)row * 32 + (idx & 31)];
        ((float4*)xs)[idx] = v;
    }
    // stage W rows 0..63 (2048 float4)
#pragma unroll
    for (int it = 0; it < 8; ++it)
        ((float4*)ws)[t + it * 256] = W4[t + it * 256];
    __syncthreads();

    int rgrp = t >> 5, c32 = t & 31;
    float4 acc[4];
#pragma unroll
    for (int i = 0; i < 4; ++i) acc[i] = make_float4(0.f, 0.f, 0.f, 0.f);

    const float4* xs4 = (const float4*)xs;
    const float4* ws4 = (const float4*)ws;

    // phase 0: k = 0..63
#pragma unroll 4
    for (int k4 = 0; k4 < 16; ++k4) {
        float4 xv[4];
#pragma unroll
        for (int i = 0; i < 4; ++i) xv[i] = xs4[(rgrp * 4 + i) * 32 + k4];
#pragma unroll
        for (int kk = 0; kk < 4; ++kk) {
            float4 w = ws4[(k4 * 4 + kk) * 32 + c32];
#pragma unroll
            for (int i = 0; i < 4; ++i) {
                float xk = (&xv[i].x)[kk];
                acc[i].x += xk * w.x; acc[i].y += xk * w.y;
                acc[i].z += xk * w.z; acc[i].w += xk * w.w;
            }
        }
    }
    __syncthreads();
    // stage W rows 64..127
#pragma unroll
    for (int it = 0; it < 8; ++it)
        ((float4*)ws)[t + it * 256] = W4[2048 + t + it * 256];
    __syncthreads();

    // phase 1: k = 64..127
#pragma unroll 4
    for (int k4 = 0; k4 < 16; ++k4) {
        float4 xv[4];
#pragma unroll
        for (int i = 0; i < 4; ++i) xv[i] = xs4[(rgrp * 4 + i) * 32 + 16 + k4];
#pragma unroll
        for (int kk = 0; kk < 4; ++kk) {
            float4 w = ws4[(k4 * 4 + kk) * 32 + c32];
#pragma unroll
            for (int i = 0; i < 4; ++i) {
                float xk = (&xv[i].x)[kk];
                acc[i].x += xk * w.x; acc[i].y += xk * w.y;
                acc[i].z += xk * w.z; acc[i].w += xk * w.w;
            }
        }
    }

    // epilogue: store H rows + fused alpha reductions
    float4 as4 = ((const float4*)a_src)[c32];
    float4 ad4 = ((const float4*)a_dst)[c32];
#pragma unroll
    for (int i = 0; i < 4; ++i) {
        int row = rowBase + rgrp * 4 + i;
        if (row >= n) continue;
        ((float4*)(H + (size_t)row * 128))[c32] = acc[i];
        float ps = acc[i].x * as4.x + acc[i].y * as4.y + acc[i].z * as4.z + acc[i].w * as4.w;
        float pd = acc[i].x * ad4.x + acc[i].y * ad4.y + acc[i].z * ad4.z + acc[i].w * ad4.w;
#pragma unroll
        for (int m = 8; m >= 1; m >>= 1) {
            ps += __shfl_xor(ps, m, 16);
            pd += __shfl_xor(pd, m, 16);
        }
        if ((c32 & 15) == 0) {
            int head = c32 >> 4;
            as_out[row * 2 + head] = ps;
            ad_out[row * 2 + head] = pd;
        }
    }
}

// Aggregation: one wave per node. lane c holds head0 ch c and head1 ch c.
__global__ __launch_bounds__(256) void k_agg(
    const float* __restrict__ H, const float* __restrict__ as,
    const float* __restrict__ ad, const float* __restrict__ bias,
    const int* __restrict__ csr, const int* __restrict__ off,
    const int* __restrict__ deg, float* __restrict__ out, int n) {
    int wave = threadIdx.x >> 6, lane = threadIdx.x & 63;
    int node = blockIdx.x * 4 + wave;
    if (node >= n) return;
    int o = off[node], d = deg[node];
    float ad0 = ad[node * 2], ad1 = ad[node * 2 + 1];
    float acc0 = 0.f, acc1 = 0.f, den0 = 0.f, den1 = 0.f;
    for (int j = 0; j < d; ++j) {
        int s = csr[o + j];
        float as0 = as[s * 2], as1 = as[s * 2 + 1];
        float e0 = as0 + ad0; e0 = e0 >= 0.f ? e0 : 0.2f * e0;
        float e1 = as1 + ad1; e1 = e1 >= 0.f ? e1 : 0.2f * e1;
        float w0 = __expf(e0), w1 = __expf(e1);
        den0 += w0; den1 += w1;
        const float* hrow = H + (size_t)s * 128;
        acc0 += w0 * hrow[lane];
        acc1 += w1 * hrow[64 + lane];
    }
    float r0 = acc0 / den0 + bias[lane];
    float r1 = acc1 / den1 + bias[64 + lane];
    r0 = r0 > 0.f ? r0 : __expf(r0) - 1.f;   // ELU
    r1 = r1 > 0.f ? r1 : __expf(r1) - 1.f;
    out[(size_t)node * 128 + lane] = r0;
    out[(size_t)node * 128 + 64 + lane] = r1;
}

extern "C" void kernel_launch(void* const* d_in, const int* in_sizes, int n_in,
                              void* d_out, int out_size, void* d_ws, size_t ws_size,
                              hipStream_t stream) {
    const float* x   = (const float*)d_in[0];
    const int*   ei  = (const int*)d_in[1];
    const float* W1  = (const float*)d_in[2];
    const float* as1 = (const float*)d_in[3];
    const float* ad1 = (const float*)d_in[4];
    const float* b1  = (const float*)d_in[5];
    const float* W2  = (const float*)d_in[6];
    const float* as2 = (const float*)d_in[7];
    const float* ad2 = (const float*)d_in[8];
    const float* b2  = (const float*)d_in[9];

    const int N = in_sizes[0] / 128;
    const int E = in_sizes[1] / 2;

    // workspace carve-up
    float* h       = (float*)d_ws;                 // N*128
    float* y1      = h + (size_t)N * 128;          // N*128
    float* alpha_s = y1 + (size_t)N * 128;         // 2N
    float* alpha_d = alpha_s + 2 * (size_t)N;      // 2N
    int*   deg     = (int*)(alpha_d + 2 * (size_t)N);
    int*   off     = deg + N;
    int*   cursor  = off + N;
    int*   bsum    = cursor + N;                   // 128
    int*   csr     = bsum + 128;                   // E+N

    hipMemsetAsync(deg, 0, (size_t)N * 4, stream);
    hipMemsetAsync(cursor, 0, (size_t)N * 4, stream);

    int nb = (N + 1023) / 1024;
    k_hist<<<(E + N + 255) / 256, 256, 0, stream>>>(ei, deg, E, N);
    k_scan_block<<<nb, 1024, 0, stream>>>(deg, off, bsum, N);
    k_scan_bsum<<<1, 128, 0, stream>>>(bsum, nb);
    k_scan_add<<<nb, 1024, 0, stream>>>(off, bsum, N);
    k_scatter<<<(E + N + 255) / 256, 256, 0, stream>>>(ei, off, cursor, csr, E, N);

    // layer 1
    k_gemm_alpha<<<(N + 31) / 32, 256, 0, stream>>>(x, W1, as1, ad1, h, alpha_s, alpha_d, N);
    k_agg<<<(N + 3) / 4, 256, 0, stream>>>(h, alpha_s, alpha_d, b1, csr, off, deg, y1, N);

    // layer 2
    k_gemm_alpha<<<(N + 31) / 32, 256, 0, stream>>>(y1, W2, as2, ad2, h, alpha_s, alpha_d, N);
    k_agg<<<(N + 3) / 4, 256, 0, stream>>>(h, alpha_s, alpha_d, b2, csr, off, deg, (float*)d_out, N);
}

// Round 3
// 641.450 us; speedup vs baseline: 1.6522x; 1.2257x over previous
//
#include <hip/hip_runtime.h>

// ---------------------------------------------------------------------------
// GAT encoder, 2 layers, N=100K nodes, E=1.6M edges (+N self loops), F=128,
// heads=2 x 64ch. Strategy:
//   1. Build dst-CSR once (histogram -> scan -> scatter), reused by both layers.
//   2. Per layer: fp32 GEMM h = x@W (W staged in LDS, 4x4 register blocking)
//      with fused alpha_src/alpha_dst epilogue, then per-node wave aggregation
//      (4-way unrolled edge loop for memory-level parallelism):
//      out = elu( sum_e w_e h[src_e] / sum_e w_e + b ).
//   Softmax max-subtraction skipped (logits bounded ~|2|, exp safe in fp32).
// ---------------------------------------------------------------------------

__global__ __launch_bounds__(256) void k_hist(const int* __restrict__ ei,
                                              int* __restrict__ deg, int E, int n) {
    int i = blockIdx.x * blockDim.x + threadIdx.x;
    if (i < E) {
        atomicAdd(&deg[ei[E + i]], 1);          // dst half of edge_index
    } else if (i < E + n) {
        atomicAdd(&deg[i - E], 1);              // self loop
    }
}

__global__ __launch_bounds__(1024) void k_scan_block(const int* __restrict__ deg,
                                                     int* __restrict__ off,
                                                     int* __restrict__ bsum, int n) {
    __shared__ int tmp[1024];
    int t = threadIdx.x;
    int i = blockIdx.x * 1024 + t;
    int v = (i < n) ? deg[i] : 0;
    tmp[t] = v;
    __syncthreads();
    for (int d = 1; d < 1024; d <<= 1) {
        int a = (t >= d) ? tmp[t - d] : 0;
        __syncthreads();
        tmp[t] += a;
        __syncthreads();
    }
    if (i < n) off[i] = tmp[t] - v;             // exclusive
    if (t == 1023) bsum[blockIdx.x] = tmp[t];
}

__global__ __launch_bounds__(128) void k_scan_bsum(int* __restrict__ bsum, int nb) {
    __shared__ int tmp[128];
    int t = threadIdx.x;
    int v = (t < nb) ? bsum[t] : 0;
    tmp[t] = v;
    __syncthreads();
    for (int d = 1; d < 128; d <<= 1) {
        int a = (t >= d) ? tmp[t - d] : 0;
        __syncthreads();
        tmp[t] += a;
        __syncthreads();
    }
    if (t < nb) bsum[t] = tmp[t] - v;           // exclusive over block sums
}

__global__ __launch_bounds__(1024) void k_scan_add(int* __restrict__ off,
                                                   const int* __restrict__ bsum, int n) {
    int i = blockIdx.x * 1024 + threadIdx.x;
    if (i < n) off[i] += bsum[blockIdx.x];
}

__global__ __launch_bounds__(256) void k_scatter(const int* __restrict__ ei,
                                                 const int* __restrict__ off,
                                                 int* __restrict__ cursor,
                                                 int* __restrict__ csr, int E, int n) {
    int i = blockIdx.x * blockDim.x + threadIdx.x;
    if (i < E) {
        int d = ei[E + i];
        int p = atomicAdd(&cursor[d], 1);
        csr[off[d] + p] = ei[i];
    } else if (i < E + n) {
        int nn = i - E;
        int p = atomicAdd(&cursor[nn], 1);
        csr[off[nn] + p] = nn;
    }
}

// GEMM: H[row,col] = sum_k X[row,k]*W[k,col], W 128x128 staged in LDS (two
// 64-row k-halves), X tile 32 rows in LDS, acc[4][4] register blocking.
__global__ __launch_bounds__(256) void k_gemm_alpha(
    const float* __restrict__ X, const float* __restrict__ W,
    const float* __restrict__ a_src, const float* __restrict__ a_dst,
    float* __restrict__ H, float* __restrict__ as_out, float* __restrict__ ad_out,
    int n) {
    __shared__ float xs[32 * 128];   // 16 KB
    __shared__ float ws[64 * 128];   // 32 KB (one k-half of W at a time)
    int t = threadIdx.x;
    int rowBase = blockIdx.x * 32;
    const float4* X4 = (const float4*)X;
    const float4* W4 = (const float4*)W;

    // stage X tile (32 rows x 128 = 1024 float4)
#pragma unroll
    for (int it = 0; it < 4; ++it) {
        int idx = t + it * 256;
        int row = rowBase + (idx >> 5);
        float4 v = make_float4(0.f, 0.f, 0.f, 0.f);
        if (row < n) v = X4[(size_t)row * 32 + (idx & 31)];
        ((float4*)xs)[idx] = v;
    }
    // stage W rows 0..63 (2048 float4)
#pragma unroll
    for (int it = 0; it < 8; ++it)
        ((float4*)ws)[t + it * 256] = W4[t + it * 256];
    __syncthreads();

    int rgrp = t >> 5, c32 = t & 31;
    float4 acc[4];
#pragma unroll
    for (int i = 0; i < 4; ++i) acc[i] = make_float4(0.f, 0.f, 0.f, 0.f);

    const float4* xs4 = (const float4*)xs;
    const float4* ws4 = (const float4*)ws;

    // phase 0: k = 0..63
#pragma unroll 4
    for (int k4 = 0; k4 < 16; ++k4) {
        float4 xv[4];
#pragma unroll
        for (int i = 0; i < 4; ++i) xv[i] = xs4[(rgrp * 4 + i) * 32 + k4];
#pragma unroll
        for (int kk = 0; kk < 4; ++kk) {
            float4 w = ws4[(k4 * 4 + kk) * 32 + c32];
#pragma unroll
            for (int i = 0; i < 4; ++i) {
                float xk = (&xv[i].x)[kk];
                acc[i].x += xk * w.x; acc[i].y += xk * w.y;
                acc[i].z += xk * w.z; acc[i].w += xk * w.w;
            }
        }
    }
    __syncthreads();
    // stage W rows 64..127
#pragma unroll
    for (int it = 0; it < 8; ++it)
        ((float4*)ws)[t + it * 256] = W4[2048 + t + it * 256];
    __syncthreads();

    // phase 1: k = 64..127
#pragma unroll 4
    for (int k4 = 0; k4 < 16; ++k4) {
        float4 xv[4];
#pragma unroll
        for (int i = 0; i < 4; ++i) xv[i] = xs4[(rgrp * 4 + i) * 32 + 16 + k4];
#pragma unroll
        for (int kk = 0; kk < 4; ++kk) {
            float4 w = ws4[(k4 * 4 + kk) * 32 + c32];
#pragma unroll
            for (int i = 0; i < 4; ++i) {
                float xk = (&xv[i].x)[kk];
                acc[i].x += xk * w.x; acc[i].y += xk * w.y;
                acc[i].z += xk * w.z; acc[i].w += xk * w.w;
            }
        }
    }

    // epilogue: store H rows + fused alpha reductions
    float4 as4 = ((const float4*)a_src)[c32];
    float4 ad4 = ((const float4*)a_dst)[c32];
#pragma unroll
    for (int i = 0; i < 4; ++i) {
        int row = rowBase + rgrp * 4 + i;
        if (row >= n) continue;
        ((float4*)(H + (size_t)row * 128))[c32] = acc[i];
        float ps = acc[i].x * as4.x + acc[i].y * as4.y + acc[i].z * as4.z + acc[i].w * as4.w;
        float pd = acc[i].x * ad4.x + acc[i].y * ad4.y + acc[i].z * ad4.z + acc[i].w * ad4.w;
#pragma unroll
        for (int m = 8; m >= 1; m >>= 1) {
            ps += __shfl_xor(ps, m, 16);
            pd += __shfl_xor(pd, m, 16);
        }
        if ((c32 & 15) == 0) {
            int head = c32 >> 4;
            as_out[row * 2 + head] = ps;
            ad_out[row * 2 + head] = pd;
        }
    }
}

// Aggregation: one wave per node, 4-way unrolled edge loop (4 independent
// gather chains in flight). lane c holds head0 ch c and head1 ch c.
__global__ __launch_bounds__(256) void k_agg(
    const float* __restrict__ H, const float* __restrict__ as,
    const float* __restrict__ ad, const float* __restrict__ bias,
    const int* __restrict__ csr, const int* __restrict__ off,
    const int* __restrict__ deg, float* __restrict__ out, int n) {
    int wave = threadIdx.x >> 6, lane = threadIdx.x & 63;
    int node = blockIdx.x * 4 + wave;
    if (node >= n) return;
    int o = off[node], d = deg[node];
    float ad0 = ad[node * 2], ad1 = ad[node * 2 + 1];
    float acc0 = 0.f, acc1 = 0.f, den0 = 0.f, den1 = 0.f;
    int j = 0;
    for (; j + 4 <= d; j += 4) {
        // slot indices (wave-uniform -> scalar loads)
        int s0 = csr[o + j], s1 = csr[o + j + 1];
        int s2 = csr[o + j + 2], s3 = csr[o + j + 3];
        // issue all gathers before consuming anything
        const float* h0 = H + (size_t)s0 * 128;
        const float* h1 = H + (size_t)s1 * 128;
        const float* h2 = H + (size_t)s2 * 128;
        const float* h3 = H + (size_t)s3 * 128;
        float2 a0 = *(const float2*)(as + s0 * 2);
        float2 a1 = *(const float2*)(as + s1 * 2);
        float2 a2 = *(const float2*)(as + s2 * 2);
        float2 a3 = *(const float2*)(as + s3 * 2);
        float g0x = h0[lane], g0y = h0[64 + lane];
        float g1x = h1[lane], g1y = h1[64 + lane];
        float g2x = h2[lane], g2y = h2[64 + lane];
        float g3x = h3[lane], g3y = h3[64 + lane];
        // consume
        float e;
        e = a0.x + ad0; e = e >= 0.f ? e : 0.2f * e; float w00 = __expf(e);
        e = a0.y + ad1; e = e >= 0.f ? e : 0.2f * e; float w01 = __expf(e);
        e = a1.x + ad0; e = e >= 0.f ? e : 0.2f * e; float w10 = __expf(e);
        e = a1.y + ad1; e = e >= 0.f ? e : 0.2f * e; float w11 = __expf(e);
        e = a2.x + ad0; e = e >= 0.f ? e : 0.2f * e; float w20 = __expf(e);
        e = a2.y + ad1; e = e >= 0.f ? e : 0.2f * e; float w21 = __expf(e);
        e = a3.x + ad0; e = e >= 0.f ? e : 0.2f * e; float w30 = __expf(e);
        e = a3.y + ad1; e = e >= 0.f ? e : 0.2f * e; float w31 = __expf(e);
        den0 += w00 + w10 + w20 + w30;
        den1 += w01 + w11 + w21 + w31;
        acc0 += w00 * g0x + w10 * g1x + w20 * g2x + w30 * g3x;
        acc1 += w01 * g0y + w11 * g1y + w21 * g2y + w31 * g3y;
    }
    for (; j < d; ++j) {
        int s = csr[o + j];
        float2 a = *(const float2*)(as + s * 2);
        const float* hrow = H + (size_t)s * 128;
        float e0 = a.x + ad0; e0 = e0 >= 0.f ? e0 : 0.2f * e0;
        float e1 = a.y + ad1; e1 = e1 >= 0.f ? e1 : 0.2f * e1;
        float w0 = __expf(e0), w1 = __expf(e1);
        den0 += w0; den1 += w1;
        acc0 += w0 * hrow[lane];
        acc1 += w1 * hrow[64 + lane];
    }
    float r0 = acc0 / den0 + bias[lane];
    float r1 = acc1 / den1 + bias[64 + lane];
    r0 = r0 > 0.f ? r0 : __expf(r0) - 1.f;   // ELU
    r1 = r1 > 0.f ? r1 : __expf(r1) - 1.f;
    out[(size_t)node * 128 + lane] = r0;
    out[(size_t)node * 128 + 64 + lane] = r1;
}

extern "C" void kernel_launch(void* const* d_in, const int* in_sizes, int n_in,
                              void* d_out, int out_size, void* d_ws, size_t ws_size,
                              hipStream_t stream) {
    const float* x   = (const float*)d_in[0];
    const int*   ei  = (const int*)d_in[1];
    const float* W1  = (const float*)d_in[2];
    const float* as1 = (const float*)d_in[3];
    const float* ad1 = (const float*)d_in[4];
    const float* b1  = (const float*)d_in[5];
    const float* W2  = (const float*)d_in[6];
    const float* as2 = (const float*)d_in[7];
    const float* ad2 = (const float*)d_in[8];
    const float* b2  = (const float*)d_in[9];

    const int N = in_sizes[0] / 128;
    const int E = in_sizes[1] / 2;

    // workspace carve-up
    float* h       = (float*)d_ws;                 // N*128
    float* y1      = h + (size_t)N * 128;          // N*128
    float* alpha_s = y1 + (size_t)N * 128;         // 2N
    float* alpha_d = alpha_s + 2 * (size_t)N;      // 2N
    int*   deg     = (int*)(alpha_d + 2 * (size_t)N);
    int*   off     = deg + N;
    int*   cursor  = off + N;
    int*   bsum    = cursor + N;                   // 128
    int*   csr     = bsum + 128;                   // E+N

    hipMemsetAsync(deg, 0, (size_t)N * 4, stream);
    hipMemsetAsync(cursor, 0, (size_t)N * 4, stream);

    int nb = (N + 1023) / 1024;
    k_hist<<<(E + N + 255) / 256, 256, 0, stream>>>(ei, deg, E, N);
    k_scan_block<<<nb, 1024, 0, stream>>>(deg, off, bsum, N);
    k_scan_bsum<<<1, 128, 0, stream>>>(bsum, nb);
    k_scan_add<<<nb, 1024, 0, stream>>>(off, bsum, N);
    k_scatter<<<(E + N + 255) / 256, 256, 0, stream>>>(ei, off, cursor, csr, E, N);

    // layer 1
    k_gemm_alpha<<<(N + 31) / 32, 256, 0, stream>>>(x, W1, as1, ad1, h, alpha_s, alpha_d, N);
    k_agg<<<(N + 3) / 4, 256, 0, stream>>>(h, alpha_s, alpha_d, b1, csr, off, deg, y1, N);

    // layer 2
    k_gemm_alpha<<<(N + 31) / 32, 256, 0, stream>>>(y1, W2, as2, ad2, h, alpha_s, alpha_d, N);
    k_agg<<<(N + 3) / 4, 256, 0, stream>>>(h, alpha_s, alpha_d, b2, csr, off, deg, (float*)d_out, N);
}